// Round 1
// baseline (1321.001 us; speedup 1.0000x reference)
//
#include <hip/hip_runtime.h>

#define T_TOK 16384
#define DMODEL 1024
#define DFF 4096
#define NEXP 8
#define BM 128
#define BN 128
#define BK 32
#define LDA 40   // fallback path: BK + 8 bf16 pad
#define LDB 40
#define TPAD (T_TOK + NEXP * BM)   // 17408 (legacy 128-pad path)

// ---- 8-phase path geometry ----
#define SEG8 256
#define TP256 (T_TOK + NEXP * SEG8)  // 18432, 72 row-tiles of 256 (72 = 9*8, XCD-bijective)
#define BM8 256
#define BN8 128
#define BK8 64

typedef __bf16 bf16x8 __attribute__((ext_vector_type(8)));
typedef float f32x4 __attribute__((ext_vector_type(4)));

// async global->LDS, 16B per lane; LDS dest = wave-uniform base + lane*16
#define GLOAD16(gp, lp) __builtin_amdgcn_global_load_lds( \
    (const __attribute__((address_space(1))) void*)(gp), \
    (__attribute__((address_space(3))) void*)(lp), 16, 0, 0)

#define MFMA16(a, b, c) __builtin_amdgcn_mfma_f32_16x16x32_bf16(a, b, c, 0, 0, 0)

__device__ __forceinline__ float gelu_f(float x) {
  float u = 0.7978845608028654f * (x + 0.044715f * x * x * x);
  float e = __expf(2.0f * u);
  float th = 1.0f - 2.0f / (e + 1.0f);
  return 0.5f * x * (1.0f + th);
}

// ---------------- routing ----------------
__global__ void k_init(int* counts, int* cursors, int* bucket, int n) {
  int i = blockIdx.x * blockDim.x + threadIdx.x;
  if (i < n) bucket[i] = -1;
  if (i < NEXP) { counts[i] = 0; cursors[i] = 0; }
}

__global__ void k_hist(const int* __restrict__ idx, int* counts) {
  int t = blockIdx.x * blockDim.x + threadIdx.x;
  if (t < T_TOK) atomicAdd(&counts[idx[t]], 1);
}

__global__ void k_scan(const int* __restrict__ counts, int* po, int seg) {
  if (threadIdx.x == 0 && blockIdx.x == 0) {
    int acc = 0;
    for (int e = 0; e < NEXP; e++) {
      po[e] = acc;
      acc += ((counts[e] + seg - 1) / seg) * seg;
    }
    po[NEXP] = acc;
  }
}

__global__ void k_scatter(const int* __restrict__ idx, const int* __restrict__ po,
                          int* cursors, int* bucket) {
  int t = blockIdx.x * blockDim.x + threadIdx.x;
  if (t < T_TOK) {
    int e = idx[t];
    int p = atomicAdd(&cursors[e], 1);
    bucket[po[e] + p] = t;
  }
}

// ---------------- pre-passes ----------------
__global__ __launch_bounds__(256) void k_gather(
    const float* __restrict__ X, const int* __restrict__ bucket,
    __bf16* __restrict__ Xg)
{
  const int r = blockIdx.x;
  const int t = bucket[r];
  const int c = threadIdx.x * 4;
  float4 v = {0.f, 0.f, 0.f, 0.f};
  if (t >= 0) v = *(const float4*)&X[(size_t)t * DMODEL + c];
  union { __bf16 h[4]; uint2 u; } cv;
  cv.h[0] = (__bf16)v.x; cv.h[1] = (__bf16)v.y;
  cv.h[2] = (__bf16)v.z; cv.h[3] = (__bf16)v.w;
  *(uint2*)&Xg[(size_t)r * DMODEL + c] = cv.u;
}

// W [e][K][N] fp32 -> Wt [e][N][K] bf16 (64x64 LDS tile transpose)
__global__ __launch_bounds__(256) void k_transpose(
    const float* __restrict__ W, __bf16* __restrict__ Wt, int K, int N)
{
  __shared__ float tile[64][65];
  const size_t msz = (size_t)K * N;
  const float* __restrict__ src = W + (size_t)blockIdx.z * msz;
  __bf16* __restrict__ dst = Wt + (size_t)blockIdx.z * msz;
  const int n0 = blockIdx.x * 64, k0 = blockIdx.y * 64;
  const int tc = threadIdx.x & 15, tr = threadIdx.x >> 4;
#pragma unroll
  for (int i = 0; i < 4; i++) {
    float4 v = *(const float4*)&src[(size_t)(k0 + tr + i * 16) * N + n0 + tc * 4];
    tile[tr + i * 16][tc * 4 + 0] = v.x;
    tile[tr + i * 16][tc * 4 + 1] = v.y;
    tile[tr + i * 16][tc * 4 + 2] = v.z;
    tile[tr + i * 16][tc * 4 + 3] = v.w;
  }
  __syncthreads();
#pragma unroll
  for (int i = 0; i < 4; i++) {
    const int n = tr + i * 16;
    union { __bf16 h[4]; uint2 u; } cv;
    cv.h[0] = (__bf16)tile[tc * 4 + 0][n];
    cv.h[1] = (__bf16)tile[tc * 4 + 1][n];
    cv.h[2] = (__bf16)tile[tc * 4 + 2][n];
    cv.h[3] = (__bf16)tile[tc * 4 + 3][n];
    *(uint2*)&dst[(size_t)(n0 + n) * K + k0 + tc * 4] = cv.u;
  }
}

// =====================================================================
// 8-phase 256x128 GEMM, BK=64, 8 waves (2M x 4N), 3-deep LDS pipeline.
//   - per iteration: stage tile kt+2 (6 global_load_lds) interleaved over
//     4 phases; compute tile kt from buffer cb; boundary s_waitcnt vmcnt(6)
//     guarantees tile kt+1 resident (all but newest 6 retired). Never
//     drains to 0 in steady state (T4).
//   - raw s_barrier (no __syncthreads -> no forced vmcnt(0) drain).
//   - LDS rows are 128B; slot swizzle phys = logical ^ (row&7) applied on
//     BOTH sides: pre-swizzled global source (gload_lds writes linearly)
//     and swizzled ds_read address (rule 21 / T2).
//   - setprio(1) around each 8-MFMA cluster (T5).
// =====================================================================
#define PHASE_A(IB, AROW)                                                    \
  {                                                                          \
    bf16x8 a00 = *(const bf16x8*)&Ac[((AROW) + 0) * BK8 + s0 * 8];           \
    bf16x8 a01 = *(const bf16x8*)&Ac[((AROW) + 0) * BK8 + s1 * 8];           \
    bf16x8 a10 = *(const bf16x8*)&Ac[((AROW) + 16) * BK8 + s0 * 8];          \
    bf16x8 a11 = *(const bf16x8*)&Ac[((AROW) + 16) * BK8 + s1 * 8];          \
    __builtin_amdgcn_s_barrier();                                            \
    __builtin_amdgcn_s_setprio(1);                                           \
    acc[IB][0]     = MFMA16(a00, b00, acc[IB][0]);                           \
    acc[IB][0]     = MFMA16(a01, b01, acc[IB][0]);                           \
    acc[IB][1]     = MFMA16(a00, b10, acc[IB][1]);                           \
    acc[IB][1]     = MFMA16(a01, b11, acc[IB][1]);                           \
    acc[IB + 1][0] = MFMA16(a10, b00, acc[IB + 1][0]);                       \
    acc[IB + 1][0] = MFMA16(a11, b01, acc[IB + 1][0]);                       \
    acc[IB + 1][1] = MFMA16(a10, b10, acc[IB + 1][1]);                       \
    acc[IB + 1][1] = MFMA16(a11, b11, acc[IB + 1][1]);                       \
    __builtin_amdgcn_s_setprio(0);                                           \
    __builtin_amdgcn_s_barrier();                                            \
  }

template <int K, int NCT, bool SCATTER>
__global__ __launch_bounds__(512, 1) void k_gemm8p(
    const __bf16* __restrict__ Ag, const __bf16* __restrict__ Wt,
    const float* __restrict__ bias, const int* __restrict__ bucket,
    const int* __restrict__ po, void* __restrict__ outp)
{
  __shared__ __align__(16) __bf16 As[3][BM8 * BK8];  // 3 x 32KB
  __shared__ __align__(16) __bf16 Bs[3][BN8 * BK8];  // 3 x 16KB
  __shared__ int toks[BM8];

  const int tid = threadIdx.x;
  const int b = (int)blockIdx.x;
  // XCD-bijective swizzle: xcd = b&7 pins a row-strip per XCD; col tiles
  // sweep within the XCD (A strip L2-resident). 72 row tiles = 9*8 -> bijective.
  const int idx = b >> 3;
  const int row_t = (b & 7) + ((idx / NCT) << 3);
  const int col_t = idx % NCT;
  const int row0 = row_t * BM8;
  if (row0 >= po[NEXP]) return;
  const int nb0 = col_t * BN8;

  int e = 0;
#pragma unroll
  for (int k = 1; k < NEXP; k++) e = (row0 >= po[k]) ? k : e;
  const __bf16* __restrict__ Bw = Wt + (size_t)e * (size_t)(NCT * BN8) * K;

  if constexpr (SCATTER) {
    if (tid < BM8) toks[tid] = bucket[row0 + tid];
    // drain so the token load never perturbs the counted-vmcnt accounting
    asm volatile("s_waitcnt vmcnt(0) lgkmcnt(0)" ::: "memory");
  }

  const int wave = tid >> 6;
  const int lane = tid & 63;
  const int wm = wave >> 2;        // 0..1 -> 128-row half
  const int wn = wave & 3;         // 0..3 -> 32-col strip
  const int lm = lane & 15;
  const int lq = lane >> 4;
  const int s0 = lq ^ (lm & 7);    // phys slot for kk=0 (row&7 == lm&7 for all frag rows)
  const int s1 = s0 ^ 4;           // phys slot for kk=1
  const int arow = wm * 128 + lm;
  const int brow = wn * 32 + lm;

  // staging: thread -> (row sr, phys slot tid&7); source slot = phys ^ (row&7)
  const int sr = tid >> 3;                 // 0..63
  const int sl = (tid & 7) ^ (sr & 7);
  const __bf16* __restrict__ Asrc = Ag + (size_t)(row0 + sr) * K + sl * 8;
  const __bf16* __restrict__ Bsrc = Bw + (size_t)(nb0 + sr) * K + sl * 8;

  f32x4 acc[8][2];
#pragma unroll
  for (int i = 0; i < 8; i++) { acc[i][0] = (f32x4)0.f; acc[i][1] = (f32x4)0.f; }

  constexpr int NT = K / BK8;

  // prologue: stage tiles 0,1 -> buffers 0,1 (12 loads), retire tile 0
#pragma unroll
  for (int c = 0; c < 4; c++)
    GLOAD16(Asrc + (size_t)(c * 64) * K, As[0] + c * 4096 + tid * 8);
#pragma unroll
  for (int c = 0; c < 2; c++)
    GLOAD16(Bsrc + (size_t)(c * 64) * K, Bs[0] + c * 4096 + tid * 8);
#pragma unroll
  for (int c = 0; c < 4; c++)
    GLOAD16(Asrc + (size_t)(c * 64) * K + BK8, As[1] + c * 4096 + tid * 8);
#pragma unroll
  for (int c = 0; c < 2; c++)
    GLOAD16(Bsrc + (size_t)(c * 64) * K + BK8, Bs[1] + c * 4096 + tid * 8);
  asm volatile("s_waitcnt vmcnt(6)" ::: "memory");
  __builtin_amdgcn_s_barrier();

  int cb = 0, sb = 2;
  for (int kt = 0; kt < NT; ++kt) {
    const bool st = (kt + 2 < NT);
    const size_t koff = (size_t)(kt + 2) * BK8;
    const __bf16* __restrict__ Ac = As[cb];
    const __bf16* __restrict__ Bc = Bs[cb];
    __bf16* Adst = As[sb] + tid * 8;
    __bf16* Bdst = Bs[sb] + tid * 8;
    bf16x8 b00, b01, b10, b11;

    // ---- phase 0: stage A rows 0-127 of tile kt+2; compute acc[0..1] ----
    if (st) {
      GLOAD16(Asrc + koff, Adst);
      GLOAD16(Asrc + koff + (size_t)64 * K, Adst + 4096);
    }
    {
      b00 = *(const bf16x8*)&Bc[(brow + 0) * BK8 + s0 * 8];
      b01 = *(const bf16x8*)&Bc[(brow + 0) * BK8 + s1 * 8];
      b10 = *(const bf16x8*)&Bc[(brow + 16) * BK8 + s0 * 8];
      b11 = *(const bf16x8*)&Bc[(brow + 16) * BK8 + s1 * 8];
      bf16x8 a00 = *(const bf16x8*)&Ac[(arow + 0) * BK8 + s0 * 8];
      bf16x8 a01 = *(const bf16x8*)&Ac[(arow + 0) * BK8 + s1 * 8];
      bf16x8 a10 = *(const bf16x8*)&Ac[(arow + 16) * BK8 + s0 * 8];
      bf16x8 a11 = *(const bf16x8*)&Ac[(arow + 16) * BK8 + s1 * 8];
      __builtin_amdgcn_s_barrier();
      __builtin_amdgcn_s_setprio(1);
      acc[0][0] = MFMA16(a00, b00, acc[0][0]);
      acc[0][0] = MFMA16(a01, b01, acc[0][0]);
      acc[0][1] = MFMA16(a00, b10, acc[0][1]);
      acc[0][1] = MFMA16(a01, b11, acc[0][1]);
      acc[1][0] = MFMA16(a10, b00, acc[1][0]);
      acc[1][0] = MFMA16(a11, b01, acc[1][0]);
      acc[1][1] = MFMA16(a10, b10, acc[1][1]);
      acc[1][1] = MFMA16(a11, b11, acc[1][1]);
      __builtin_amdgcn_s_setprio(0);
      __builtin_amdgcn_s_barrier();
    }
    // ---- phase 1: stage A rows 128-255 ----
    if (st) {
      GLOAD16(Asrc + koff + (size_t)128 * K, Adst + 8192);
      GLOAD16(Asrc + koff + (size_t)192 * K, Adst + 12288);
    }
    PHASE_A(2, arow + 32)
    // ---- phase 2: stage B rows 0-63 ----
    if (st) GLOAD16(Bsrc + koff, Bdst);
    PHASE_A(4, arow + 64)
    // ---- phase 3: stage B rows 64-127 ----
    if (st) GLOAD16(Bsrc + koff + (size_t)64 * K, Bdst + 4096);
    PHASE_A(6, arow + 96)
    // ---- boundary: retire tile kt+1 (all but newest 6), keep tile kt+2 in flight ----
    if (st) { asm volatile("s_waitcnt vmcnt(6)" ::: "memory"); }
    else    { asm volatile("s_waitcnt vmcnt(0)" ::: "memory"); }
    __builtin_amdgcn_s_barrier();
    cb = (cb == 2) ? 0 : cb + 1;
    sb = (sb == 2) ? 0 : sb + 1;
  }

  // ---- epilogue ----
  constexpr int N = NCT * BN8;
  const float* __restrict__ bv = bias + (size_t)e * N;
  if constexpr (!SCATTER) {
    __bf16* __restrict__ Hq = (__bf16*)outp;
#pragma unroll
    for (int i = 0; i < 8; i++) {
      const int lr = wm * 128 + i * 16 + lq * 4;
#pragma unroll
      for (int j = 0; j < 2; j++) {
        const int col = nb0 + wn * 32 + j * 16 + lm;
        const float bb = bv[col];
#pragma unroll
        for (int r = 0; r < 4; r++)
          Hq[(size_t)(row0 + lr + r) * N + col] = (__bf16)gelu_f(acc[i][j][r] + bb);
      }
    }
  } else {
    float* __restrict__ O = (float*)outp;
#pragma unroll
    for (int i = 0; i < 8; i++) {
      const int lr = wm * 128 + i * 16 + lq * 4;
#pragma unroll
      for (int j = 0; j < 2; j++) {
        const int col = nb0 + wn * 32 + j * 16 + lm;
        const float bb = bv[col];
#pragma unroll
        for (int r = 0; r < 4; r++) {
          const int t = toks[lr + r];
          if (t >= 0) O[(size_t)t * DMODEL + col] = acc[i][j][r] + bb;
        }
      }
    }
  }
}

// ================= legacy fast path (kept as ws-budget fallback) =================
__global__ __launch_bounds__(256, 2) void k_gemm1b(
    const __bf16* __restrict__ Ag, const __bf16* __restrict__ Wt,
    const float* __restrict__ b1, const int* __restrict__ po,
    __bf16* __restrict__ H)
{
  __shared__ __align__(16) __bf16 As[BM * BK];
  __shared__ __align__(16) __bf16 Bs[BN * BK];
  const int tid = threadIdx.x;
  const int b = (int)blockIdx.x;
  const int slot = b >> 3;
  const int row_t = (b & 7) + ((slot >> 5) << 3);
  const int col_t = slot & 31;
  const int row0 = row_t * BM;
  if (row0 >= po[NEXP]) return;
  const int nb0 = col_t * BN;

  int e = 0;
#pragma unroll
  for (int k = 1; k < NEXP; k++) e = (row0 >= po[k]) ? k : e;
  const __bf16* __restrict__ B = Wt + (size_t)e * DFF * DMODEL;

  f32x4 acc[4][4];
#pragma unroll
  for (int i = 0; i < 4; i++)
#pragma unroll
    for (int j = 0; j < 4; j++) acc[i][j] = (f32x4)0.0f;

  const int wave = tid >> 6;
  const int lane = tid & 63;
  const int wm = (wave & 1) * 64;
  const int wn = (wave >> 1) * 64;
  const int lm = lane & 15;
  const int lq = lane >> 4;

  const int sr = wave * 32 + (lane >> 2);
  const int g  = (lane & 3) ^ ((lane >> 3) & 3);
  const __bf16* Aptr = Ag + (size_t)(row0 + sr) * DMODEL + g * 8;
  const __bf16* Bptr = B + (size_t)(nb0 + sr) * DMODEL + g * 8;
  __bf16* Al = &As[wave * 1024];
  __bf16* Bl = &Bs[wave * 1024];
  const int sA = (lm >> 1) & 3;

  for (int k0 = 0; k0 < DMODEL; k0 += BK) {
    GLOAD16(Aptr + k0, Al);
    GLOAD16(Aptr + k0 + 16 * DMODEL, Al + 512);
    GLOAD16(Bptr + k0, Bl);
    GLOAD16(Bptr + k0 + 16 * DMODEL, Bl + 512);
    __syncthreads();

    bf16x8 af[4], bfr[4];
#pragma unroll
    for (int i = 0; i < 4; i++)
      af[i] = *(const bf16x8*)&As[(wm + i * 16 + lm) * BK + (lq ^ sA) * 8];
#pragma unroll
    for (int j = 0; j < 4; j++)
      bfr[j] = *(const bf16x8*)&Bs[(wn + j * 16 + lm) * BK + (lq ^ sA) * 8];
#pragma unroll
    for (int i = 0; i < 4; i++)
#pragma unroll
      for (int j = 0; j < 4; j++)
        acc[i][j] = __builtin_amdgcn_mfma_f32_16x16x32_bf16(af[i], bfr[j], acc[i][j], 0, 0, 0);
    __syncthreads();
  }

  const float* __restrict__ b1e = b1 + e * DFF;
#pragma unroll
  for (int j = 0; j < 4; j++) {
    const int col = nb0 + wn + j * 16 + lm;
    const float bias = b1e[col];
#pragma unroll
    for (int i = 0; i < 4; i++) {
#pragma unroll
      for (int r = 0; r < 4; r++) {
        int row = row0 + wm + i * 16 + lq * 4 + r;
        H[(size_t)row * DFF + col] = (__bf16)gelu_f(acc[i][j][r] + bias);
      }
    }
  }
}

__global__ __launch_bounds__(256, 2) void k_gemm2b(
    const __bf16* __restrict__ H, const __bf16* __restrict__ Wt,
    const float* __restrict__ b2, const int* __restrict__ bucket,
    const int* __restrict__ po, float* __restrict__ out)
{
  __shared__ __align__(16) __bf16 As[BM * BK];
  __shared__ __align__(16) __bf16 Bs[BN * BK];
  __shared__ int toks[BM];
  const int tid = threadIdx.x;
  const int b = (int)blockIdx.x;
  const int slot = b >> 3;
  const int row_t = (b & 7) + ((slot >> 3) << 3);
  const int col_t = slot & 7;
  const int row0 = row_t * BM;
  if (row0 >= po[NEXP]) return;
  const int nb0 = col_t * BN;

  int e = 0;
#pragma unroll
  for (int k = 1; k < NEXP; k++) e = (row0 >= po[k]) ? k : e;
  const __bf16* __restrict__ B = Wt + (size_t)e * DMODEL * DFF;

  if (tid < BM) toks[tid] = bucket[row0 + tid];

  f32x4 acc[4][4];
#pragma unroll
  for (int i = 0; i < 4; i++)
#pragma unroll
    for (int j = 0; j < 4; j++) acc[i][j] = (f32x4)0.0f;

  const int wave = tid >> 6;
  const int lane = tid & 63;
  const int wm = (wave & 1) * 64;
  const int wn = (wave >> 1) * 64;
  const int lm = lane & 15;
  const int lq = lane >> 4;

  const int sr = wave * 32 + (lane >> 2);
  const int g  = (lane & 3) ^ ((lane >> 3) & 3);
  const __bf16* Aptr = H + (size_t)(row0 + sr) * DFF + g * 8;
  const __bf16* Bptr = B + (size_t)(nb0 + sr) * DFF + g * 8;
  __bf16* Al = &As[wave * 1024];
  __bf16* Bl = &Bs[wave * 1024];
  const int sA = (lm >> 1) & 3;

  for (int k0 = 0; k0 < DFF; k0 += BK) {
    GLOAD16(Aptr + k0, Al);
    GLOAD16(Aptr + k0 + 16 * DFF, Al + 512);
    GLOAD16(Bptr + k0, Bl);
    GLOAD16(Bptr + k0 + 16 * DFF, Bl + 512);
    __syncthreads();

    bf16x8 af[4], bfr[4];
#pragma unroll
    for (int i = 0; i < 4; i++)
      af[i] = *(const bf16x8*)&As[(wm + i * 16 + lm) * BK + (lq ^ sA) * 8];
#pragma unroll
    for (int j = 0; j < 4; j++)
      bfr[j] = *(const bf16x8*)&Bs[(wn + j * 16 + lm) * BK + (lq ^ sA) * 8];
#pragma unroll
    for (int i = 0; i < 4; i++)
#pragma unroll
      for (int j = 0; j < 4; j++)
        acc[i][j] = __builtin_amdgcn_mfma_f32_16x16x32_bf16(af[i], bfr[j], acc[i][j], 0, 0, 0);
    __syncthreads();
  }

  const float* __restrict__ b2e = b2 + e * DMODEL;
#pragma unroll
  for (int j = 0; j < 4; j++) {
    const int col = nb0 + wn + j * 16 + lm;
    const float bias = b2e[col];
#pragma unroll
    for (int i = 0; i < 4; i++) {
#pragma unroll
      for (int r = 0; r < 4; r++) {
        int t = toks[wm + i * 16 + lq * 4 + r];
        if (t >= 0) out[(size_t)t * DMODEL + col] = acc[i][j][r] + bias;
      }
    }
  }
}

// ================= round-1 fallback path (inline-convert GEMMs) =================
__global__ __launch_bounds__(256, 2) void k_gemm1(
    const float* __restrict__ X, const float* __restrict__ W1,
    const float* __restrict__ b1, const int* __restrict__ bucket,
    const int* __restrict__ po, __bf16* __restrict__ H, int base_row)
{
  __shared__ __bf16 As[BM * LDA];
  __shared__ __bf16 Bs[BN * LDB];
  __shared__ int toks[BM];
  const int tid = threadIdx.x;
  const int total = po[NEXP];
  const int row0 = base_row + (int)blockIdx.x * BM;
  if (row0 >= total) return;
  const int nb0 = (int)blockIdx.y * BN;
  int e = 0;
#pragma unroll
  for (int k = 1; k < NEXP; k++) e = (row0 >= po[k]) ? k : e;
  const float* __restrict__ W = W1 + (size_t)e * DMODEL * DFF;
  if (tid < BM) toks[tid] = bucket[row0 + tid];
  __syncthreads();
  f32x4 acc[4][4];
#pragma unroll
  for (int i = 0; i < 4; i++)
#pragma unroll
    for (int j = 0; j < 4; j++) acc[i][j] = (f32x4)0.0f;
  const int wave = tid >> 6, lane = tid & 63;
  const int wm = (wave & 1) * 64, wn = (wave >> 1) * 64;
  const int lm = lane & 15, lq = lane >> 4;
  const int bn = tid & 127, bkh = (tid >> 7) * 16;
  for (int k0 = 0; k0 < DMODEL; k0 += BK) {
#pragma unroll
    for (int i = 0; i < 4; i++) {
      int idx = tid + i * 256;
      int row = idx >> 3, kq = idx & 7;
      int t = toks[row];
      float4 v = {0.f, 0.f, 0.f, 0.f};
      if (t >= 0) v = *(const float4*)(X + (size_t)t * DMODEL + k0 + kq * 4);
      union { __bf16 h[4]; uint2 u; } cv;
      cv.h[0] = (__bf16)v.x; cv.h[1] = (__bf16)v.y;
      cv.h[2] = (__bf16)v.z; cv.h[3] = (__bf16)v.w;
      *(uint2*)&As[row * LDA + kq * 4] = cv.u;
    }
    {
      const float* src = W + (size_t)(k0 + bkh) * DFF + nb0 + bn;
      bf16x8 b0, b1v;
#pragma unroll
      for (int kk = 0; kk < 8; kk++) b0[kk] = (__bf16)src[(size_t)kk * DFF];
#pragma unroll
      for (int kk = 0; kk < 8; kk++) b1v[kk] = (__bf16)src[(size_t)(kk + 8) * DFF];
      *(bf16x8*)&Bs[bn * LDB + bkh] = b0;
      *(bf16x8*)&Bs[bn * LDB + bkh + 8] = b1v;
    }
    __syncthreads();
    bf16x8 af[4], bfr[4];
#pragma unroll
    for (int i = 0; i < 4; i++)
      af[i] = *(const bf16x8*)&As[(wm + i * 16 + lm) * LDA + lq * 8];
#pragma unroll
    for (int j = 0; j < 4; j++)
      bfr[j] = *(const bf16x8*)&Bs[(wn + j * 16 + lm) * LDB + lq * 8];
#pragma unroll
    for (int i = 0; i < 4; i++)
#pragma unroll
      for (int j = 0; j < 4; j++)
        acc[i][j] = __builtin_amdgcn_mfma_f32_16x16x32_bf16(af[i], bfr[j], acc[i][j], 0, 0, 0);
    __syncthreads();
  }
  const float* __restrict__ b1e = b1 + e * DFF;
  const int hbase = (int)blockIdx.x * BM;
#pragma unroll
  for (int j = 0; j < 4; j++) {
    const int col = nb0 + wn + j * 16 + lm;
    const float bias = b1e[col];
#pragma unroll
    for (int i = 0; i < 4; i++)
#pragma unroll
      for (int r = 0; r < 4; r++) {
        int row = hbase + wm + i * 16 + lq * 4 + r;
        H[(size_t)row * DFF + col] = (__bf16)gelu_f(acc[i][j][r] + bias);
      }
  }
}

__global__ __launch_bounds__(256, 2) void k_gemm2(
    const __bf16* __restrict__ H, const float* __restrict__ W2,
    const float* __restrict__ b2, const int* __restrict__ bucket,
    const int* __restrict__ po, float* __restrict__ out, int base_row)
{
  __shared__ __bf16 As[BM * LDA];
  __shared__ __bf16 Bs[BN * LDB];
  __shared__ int toks[BM];
  const int tid = threadIdx.x;
  const int total = po[NEXP];
  const int row0 = base_row + (int)blockIdx.x * BM;
  if (row0 >= total) return;
  const int nb0 = (int)blockIdx.y * BN;
  int e = 0;
#pragma unroll
  for (int k = 1; k < NEXP; k++) e = (row0 >= po[k]) ? k : e;
  const float* __restrict__ W = W2 + (size_t)e * DFF * DMODEL;
  if (tid < BM) toks[tid] = bucket[row0 + tid];
  __syncthreads();
  f32x4 acc[4][4];
#pragma unroll
  for (int i = 0; i < 4; i++)
#pragma unroll
    for (int j = 0; j < 4; j++) acc[i][j] = (f32x4)0.0f;
  const int wave = tid >> 6, lane = tid & 63;
  const int wm = (wave & 1) * 64, wn = (wave >> 1) * 64;
  const int lm = lane & 15, lq = lane >> 4;
  const int bn = tid & 127, bkh = (tid >> 7) * 16;
  const int hbase = (int)blockIdx.x * BM;
  for (int k0 = 0; k0 < DFF; k0 += BK) {
#pragma unroll
    for (int i = 0; i < 2; i++) {
      int idx = tid + i * 256;
      int row = idx >> 2, kq = idx & 3;
      bf16x8 v = *(const bf16x8*)(H + (size_t)(hbase + row) * DFF + k0 + kq * 8);
      *(bf16x8*)&As[row * LDA + kq * 8] = v;
    }
    {
      const float* src = W + (size_t)(k0 + bkh) * DMODEL + nb0 + bn;
      bf16x8 b0, b1v;
#pragma unroll
      for (int kk = 0; kk < 8; kk++) b0[kk] = (__bf16)src[(size_t)kk * DMODEL];
#pragma unroll
      for (int kk = 0; kk < 8; kk++) b1v[kk] = (__bf16)src[(size_t)(kk + 8) * DMODEL];
      *(bf16x8*)&Bs[bn * LDB + bkh] = b0;
      *(bf16x8*)&Bs[bn * LDB + bkh + 8] = b1v;
    }
    __syncthreads();
    bf16x8 af[4], bfr[4];
#pragma unroll
    for (int i = 0; i < 4; i++)
      af[i] = *(const bf16x8*)&As[(wm + i * 16 + lm) * LDA + lq * 8];
#pragma unroll
    for (int j = 0; j < 4; j++)
      bfr[j] = *(const bf16x8*)&Bs[(wn + j * 16 + lm) * LDB + lq * 8];
#pragma unroll
    for (int i = 0; i < 4; i++)
#pragma unroll
      for (int j = 0; j < 4; j++)
        acc[i][j] = __builtin_amdgcn_mfma_f32_16x16x32_bf16(af[i], bfr[j], acc[i][j], 0, 0, 0);
    __syncthreads();
  }
  const float* __restrict__ b2e = b2 + e * DMODEL;
#pragma unroll
  for (int j = 0; j < 4; j++) {
    const int col = nb0 + wn + j * 16 + lm;
    const float bias = b2e[col];
#pragma unroll
    for (int i = 0; i < 4; i++)
#pragma unroll
      for (int r = 0; r < 4; r++) {
        int t = toks[wm + i * 16 + lq * 4 + r];
        if (t >= 0) out[(size_t)t * DMODEL + col] = acc[i][j][r] + bias;
      }
  }
}

__global__ __launch_bounds__(256) void k_fallback(
    const float* __restrict__ X, const int* __restrict__ idx,
    const float* __restrict__ W1, const float* __restrict__ b1,
    const float* __restrict__ W2, const float* __restrict__ b2,
    float* __restrict__ out)
{
  __shared__ float xs[DMODEL];
  __shared__ float hs[DFF];
  const int t = blockIdx.x;
  const int e = idx[t];
  const int tid = threadIdx.x;
  const float* w1 = W1 + (size_t)e * DMODEL * DFF;
  const float* w2 = W2 + (size_t)e * DFF * DMODEL;
  for (int i = tid; i < DMODEL; i += 256) xs[i] = X[(size_t)t * DMODEL + i];
  __syncthreads();
  for (int f = tid; f < DFF; f += 256) {
    float a = 0.f;
    for (int d = 0; d < DMODEL; d++) a += xs[d] * w1[(size_t)d * DFF + f];
    hs[f] = gelu_f(a + b1[e * DFF + f]);
  }
  __syncthreads();
  for (int d = tid; d < DMODEL; d += 256) {
    float a = 0.f;
    for (int f = 0; f < DFF; f++) a += hs[f] * w2[(size_t)f * DMODEL + d];
    out[(size_t)t * DMODEL + d] = a + b2[e * DMODEL + d];
  }
}

extern "C" void kernel_launch(void* const* d_in, const int* in_sizes, int n_in,
                              void* d_out, int out_size, void* d_ws, size_t ws_size,
                              hipStream_t stream) {
  const float* X  = (const float*)d_in[0];
  const int*   EI = (const int*)d_in[1];
  const float* W1 = (const float*)d_in[2];
  const float* b1 = (const float*)d_in[3];
  const float* W2 = (const float*)d_in[4];
  const float* b2 = (const float*)d_in[5];
  float* out = (float*)d_out;

  char* ws = (char*)d_ws;
  int* counts  = (int*)(ws + 0);
  int* cursors = (int*)(ws + 32);
  int* po      = (int*)(ws + 64);
  int* bucket  = (int*)(ws + 512);

  // ---- 8-phase path (expert segments padded to 256) ----
  {
    const size_t XG_OFF2 = 512 + (size_t)TP256 * 4;                    // 74240
    const size_t WT_OFF2 = XG_OFF2 + (size_t)TP256 * DMODEL * 2;
    const size_t HF_OFF2 = WT_OFF2 + (size_t)NEXP * DMODEL * DFF * 2;
    const size_t NEED2   = HF_OFF2 + (size_t)TP256 * DFF * 2;          // ~255.9 MB
    if (ws_size >= NEED2) {
      __bf16* Xg = (__bf16*)(ws + XG_OFF2);
      __bf16* Wt = (__bf16*)(ws + WT_OFF2);
      __bf16* H  = (__bf16*)(ws + HF_OFF2);

      k_init<<<(TP256 + 255) / 256, 256, 0, stream>>>(counts, cursors, bucket, TP256);
      k_hist<<<(T_TOK + 255) / 256, 256, 0, stream>>>(EI, counts);
      k_scan<<<1, 64, 0, stream>>>(counts, po, SEG8);
      k_scatter<<<(T_TOK + 255) / 256, 256, 0, stream>>>(EI, po, cursors, bucket);
      k_gather<<<TP256, 256, 0, stream>>>(X, bucket, Xg);
      k_transpose<<<dim3(DFF / 64, DMODEL / 64, NEXP), 256, 0, stream>>>(W1, Wt, DMODEL, DFF);
      k_gemm8p<DMODEL, DFF / BN8, false>
          <<<(TP256 / BM8) * (DFF / BN8), 512, 0, stream>>>(Xg, Wt, b1, bucket, po, (void*)H);
      k_transpose<<<dim3(DMODEL / 64, DFF / 64, NEXP), 256, 0, stream>>>(W2, Wt, DFF, DMODEL);
      k_gemm8p<DFF, DMODEL / BN8, true>
          <<<(TP256 / BM8) * (DMODEL / BN8), 512, 0, stream>>>(H, Wt, b2, bucket, po, (void*)out);
      return;
    }
  }

  const int Tpad = TPAD;  // 17408

  const size_t XG_OFF = 70144;
  const size_t XG_SZ  = (size_t)Tpad * DMODEL * 2;
  const size_t WT_OFF = XG_OFF + XG_SZ;
  const size_t WT_SZ  = (size_t)NEXP * DMODEL * DFF * 2;
  const size_t HF_OFF = WT_OFF + WT_SZ;
  const size_t H_SZ   = (size_t)Tpad * DFF * 2;
  const size_t NEED   = HF_OFF + H_SZ;   // ~245.4 MB

  if (ws_size >= NEED) {
    __bf16* Xg = (__bf16*)(ws + XG_OFF);
    __bf16* Wt = (__bf16*)(ws + WT_OFF);
    __bf16* H  = (__bf16*)(ws + HF_OFF);

    k_init<<<(Tpad + 255) / 256, 256, 0, stream>>>(counts, cursors, bucket, Tpad);
    k_hist<<<(T_TOK + 255) / 256, 256, 0, stream>>>(EI, counts);
    k_scan<<<1, 64, 0, stream>>>(counts, po, BM);
    k_scatter<<<(T_TOK + 255) / 256, 256, 0, stream>>>(EI, po, cursors, bucket);
    k_gather<<<Tpad, 256, 0, stream>>>(X, bucket, Xg);
    k_transpose<<<dim3(DFF / 64, DMODEL / 64, NEXP), 256, 0, stream>>>(W1, Wt, DMODEL, DFF);
    k_gemm1b<<<(Tpad / BM) * (DFF / BN), 256, 0, stream>>>(Xg, Wt, b1, po, H);
    k_transpose<<<dim3(DMODEL / 64, DFF / 64, NEXP), 256, 0, stream>>>(W2, Wt, DFF, DMODEL);
    k_gemm2b<<<(Tpad / BM) * (DMODEL / BN), 256, 0, stream>>>(H, Wt, b2, bucket, po, out);
    return;
  }

  // ---- round-1 fallback path ----
  const size_t H_OFF = 512 + (size_t)Tpad * 4;
  __bf16* H = (__bf16*)(ws + H_OFF);
  size_t avail = (ws_size > H_OFF) ? ws_size - H_OFF : 0;
  long long crll = (long long)(avail / ((size_t)DFF * 2));
  int CR = (crll > Tpad) ? Tpad : (int)crll;
  CR -= CR % BM;
  if (CR < BM) {
    k_fallback<<<T_TOK, 256, 0, stream>>>(X, EI, W1, b1, W2, b2, out);
    return;
  }
  k_init<<<(Tpad + 255) / 256, 256, 0, stream>>>(counts, cursors, bucket, Tpad);
  k_hist<<<(T_TOK + 255) / 256, 256, 0, stream>>>(EI, counts);
  k_scan<<<1, 64, 0, stream>>>(counts, po, BM);
  k_scatter<<<(T_TOK + 255) / 256, 256, 0, stream>>>(EI, po, cursors, bucket);
  int nchunks = (Tpad + CR - 1) / CR;
  for (int c = 0; c < nchunks; c++) {
    int base = c * CR;
    int rows = Tpad - base; if (rows > CR) rows = CR;
    int mt = rows / BM;
    k_gemm1<<<dim3(mt, DFF / BN), 256, 0, stream>>>(X, W1, b1, bucket, po, H, base);
    k_gemm2<<<dim3(mt, DMODEL / BN), 256, 0, stream>>>(H, W2, b2, bucket, po, out, base);
  }
}

// Round 2
// 875.361 us; speedup vs baseline: 1.5091x; 1.5091x over previous
//
#include <hip/hip_runtime.h>

#define T_TOK 16384
#define DMODEL 1024
#define DFF 4096
#define NEXP 8
#define BM 128
#define BN 128
#define BK 32
#define LDA 40   // fallback path: BK + 8 bf16 pad
#define LDB 40
#define TPAD (T_TOK + NEXP * BM)   // 17408 (legacy 128-pad path)

// ---- 256-row-tile path geometry ----
#define SEG8 256
#define TP256 (T_TOK + NEXP * SEG8)  // 18432, 72 row-tiles of 256 (72 = 9*8, XCD-bijective)
#define BM2 256
#define BN2 128
#define BK2 64

typedef __bf16 bf16x8 __attribute__((ext_vector_type(8)));
typedef float f32x4 __attribute__((ext_vector_type(4)));

// async global->LDS, 16B per lane; LDS dest = wave-uniform base + lane*16
#define GLOAD16(gp, lp) __builtin_amdgcn_global_load_lds( \
    (const __attribute__((address_space(1))) void*)(gp), \
    (__attribute__((address_space(3))) void*)(lp), 16, 0, 0)

#define MFMA16(a, b, c) __builtin_amdgcn_mfma_f32_16x16x32_bf16(a, b, c, 0, 0, 0)

__device__ __forceinline__ float gelu_f(float x) {
  float u = 0.7978845608028654f * (x + 0.044715f * x * x * x);
  float e = __expf(2.0f * u);
  float th = 1.0f - 2.0f / (e + 1.0f);
  return 0.5f * x * (1.0f + th);
}

// ---------------- routing ----------------
__global__ void k_init(int* counts, int* cursors, int* bucket, int n) {
  int i = blockIdx.x * blockDim.x + threadIdx.x;
  if (i < n) bucket[i] = -1;
  if (i < NEXP) { counts[i] = 0; cursors[i] = 0; }
}

// ballot-aggregated histogram: one atomic per wave per expert
__global__ void k_hist(const int* __restrict__ idx, int* counts) {
  int t = blockIdx.x * blockDim.x + threadIdx.x;
  int e = (t < T_TOK) ? idx[t] : -1;
#pragma unroll
  for (int ex = 0; ex < NEXP; ex++) {
    unsigned long long m = __ballot(e == ex);
    if (((threadIdx.x & 63) == 0) && m)
      atomicAdd(&counts[ex], __popcll(m));
  }
}

__global__ void k_scan(const int* __restrict__ counts, int* po, int seg) {
  if (threadIdx.x == 0 && blockIdx.x == 0) {
    int acc = 0;
    for (int e = 0; e < NEXP; e++) {
      po[e] = acc;
      acc += ((counts[e] + seg - 1) / seg) * seg;
    }
    po[NEXP] = acc;
  }
}

// ballot-aggregated scatter: one atomic per wave per expert
__global__ void k_scatter(const int* __restrict__ idx, const int* __restrict__ po,
                          int* cursors, int* bucket) {
  int t = blockIdx.x * blockDim.x + threadIdx.x;
  int lane = threadIdx.x & 63;
  int e = (t < T_TOK) ? idx[t] : -1;
#pragma unroll
  for (int ex = 0; ex < NEXP; ex++) {
    unsigned long long m = __ballot(e == ex);
    if (e == ex) {
      int lead = __ffsll((long long)m) - 1;
      unsigned long long before = m & ((lane == 0) ? 0ull : ((1ull << lane) - 1ull));
      int base = 0;
      if (lane == lead) base = atomicAdd(&cursors[ex], __popcll(m));
      base = __shfl(base, lead);
      bucket[po[ex] + base + __popcll(before)] = t;
    }
  }
}

// ---------------- pre-passes ----------------
__global__ __launch_bounds__(256) void k_gather(
    const float* __restrict__ X, const int* __restrict__ bucket,
    __bf16* __restrict__ Xg)
{
  const int r = blockIdx.x;
  const int t = bucket[r];
  const int c = threadIdx.x * 4;
  float4 v = {0.f, 0.f, 0.f, 0.f};
  if (t >= 0) v = *(const float4*)&X[(size_t)t * DMODEL + c];
  union { __bf16 h[4]; uint2 u; } cv;
  cv.h[0] = (__bf16)v.x; cv.h[1] = (__bf16)v.y;
  cv.h[2] = (__bf16)v.z; cv.h[3] = (__bf16)v.w;
  *(uint2*)&Xg[(size_t)r * DMODEL + c] = cv.u;
}

// W [e][K][N] fp32 -> Wt [e][N][K] bf16 (64x64 LDS tile transpose)
__global__ __launch_bounds__(256) void k_transpose(
    const float* __restrict__ W, __bf16* __restrict__ Wt, int K, int N)
{
  __shared__ float tile[64][65];
  const size_t msz = (size_t)K * N;
  const float* __restrict__ src = W + (size_t)blockIdx.z * msz;
  __bf16* __restrict__ dst = Wt + (size_t)blockIdx.z * msz;
  const int n0 = blockIdx.x * 64, k0 = blockIdx.y * 64;
  const int tc = threadIdx.x & 15, tr = threadIdx.x >> 4;
#pragma unroll
  for (int i = 0; i < 4; i++) {
    float4 v = *(const float4*)&src[(size_t)(k0 + tr + i * 16) * N + n0 + tc * 4];
    tile[tr + i * 16][tc * 4 + 0] = v.x;
    tile[tr + i * 16][tc * 4 + 1] = v.y;
    tile[tr + i * 16][tc * 4 + 2] = v.z;
    tile[tr + i * 16][tc * 4 + 3] = v.w;
  }
  __syncthreads();
#pragma unroll
  for (int i = 0; i < 4; i++) {
    const int n = tr + i * 16;
    union { __bf16 h[4]; uint2 u; } cv;
    cv.h[0] = (__bf16)tile[tc * 4 + 0][n];
    cv.h[1] = (__bf16)tile[tc * 4 + 1][n];
    cv.h[2] = (__bf16)tile[tc * 4 + 2][n];
    cv.h[3] = (__bf16)tile[tc * 4 + 3][n];
    *(uint2*)&dst[(size_t)(n0 + n) * K + k0 + tc * 4] = cv.u;
  }
}

// =====================================================================
// 256x128-tile, BK=64, 2-phase GEMM (proven m97-class structure).
//   - 512 threads = 8 waves in a 4(M) x 2(N) grid; per-wave 64x64 output
//     with the verified acc[4][4] inner code.
//   - single-buffer LDS 49KB -> 2 blocks/CU (TLP hides the barrier drain,
//     as in the 962us baseline).
//   - rows are 64 bf16 = 8 kquads of 16B; phys slot = kq ^ (row&7), applied
//     on BOTH sides (pre-swizzled global source for global_load_lds, and
//     swizzled ds_read address). Bank-quads uniformly covered -> conflict-free.
//   - vs 128x128/BK=32: staged bytes per output element 1.0 -> 0.75 (the
//     measured regime is memory-system-traffic-bound at ~8 TB/s), and 2x
//     MFMA per barrier pair.
// =====================================================================
template <int K, int NCT, bool SCATTER>
__global__ __launch_bounds__(512, 4) void k_gemm2p(
    const __bf16* __restrict__ Ag, const __bf16* __restrict__ Wt,
    const float* __restrict__ bias, const int* __restrict__ bucket,
    const int* __restrict__ po, void* __restrict__ outp)
{
  __shared__ __align__(16) __bf16 As[BM2 * BK2];  // 32 KB
  __shared__ __align__(16) __bf16 Bs[BN2 * BK2];  // 16 KB
  __shared__ int toks[BM2];

  const int tid = threadIdx.x;
  const int b = (int)blockIdx.x;
  // XCD swizzle: xcd = b&7 pins a row-strip per XCD; col tiles sweep within
  // the XCD (A strip stays in that XCD's L2). 72 row tiles = 9*8 -> bijective.
  const int idx = b >> 3;
  const int row_t = (b & 7) + ((idx / NCT) << 3);
  const int col_t = idx % NCT;
  const int row0 = row_t * BM2;
  if (row0 >= po[NEXP]) return;
  const int nb0 = col_t * BN2;

  int e = 0;
#pragma unroll
  for (int k = 1; k < NEXP; k++) e = (row0 >= po[k]) ? k : e;
  const __bf16* __restrict__ Bw = Wt + (size_t)e * (size_t)(NCT * BN2) * K;

  if constexpr (SCATTER) {
    if (tid < BM2) toks[tid] = bucket[row0 + tid];
  }

  const int wave = tid >> 6;
  const int lane = tid & 63;
  const int wm = (wave >> 1) * 64;   // 4 wave-rows
  const int wn = (wave & 1) * 64;    // 2 wave-cols
  const int lm = lane & 15;
  const int lq = lane >> 4;

  // staging: instr c covers rows c*64 + wave*8 + (lane>>3), phys slot lane&7.
  // source kquad = phys ^ (row&7) = (lane&7) ^ (lane>>3)  (row base == 0 mod 8)
  const int srow = wave * 8 + (lane >> 3);
  const int skq  = (lane & 7) ^ ((lane >> 3) & 7);
  const __bf16* __restrict__ Asrc = Ag + (size_t)(row0 + srow) * K + skq * 8;
  const __bf16* __restrict__ Bsrc = Bw + (size_t)(nb0 + srow) * K + skq * 8;
  // wave-uniform LDS bases (HW adds lane*16B)
  __bf16* const Al = As + wave * 512;
  __bf16* const Bl = Bs + wave * 512;

  f32x4 acc[4][4];
#pragma unroll
  for (int i = 0; i < 4; i++)
#pragma unroll
    for (int j = 0; j < 4; j++) acc[i][j] = (f32x4)0.0f;

  const int sA = lm & 7;  // row&7 for all fragment rows

  for (int k0 = 0; k0 < K; k0 += BK2) {
    GLOAD16(Asrc + k0,                    Al);
    GLOAD16(Asrc + k0 + (size_t)64 * K,   Al + 4096);
    GLOAD16(Asrc + k0 + (size_t)128 * K,  Al + 8192);
    GLOAD16(Asrc + k0 + (size_t)192 * K,  Al + 12288);
    GLOAD16(Bsrc + k0,                    Bl);
    GLOAD16(Bsrc + k0 + (size_t)64 * K,   Bl + 4096);
    __syncthreads();

#pragma unroll
    for (int h = 0; h < 2; h++) {
      const int ph = (h * 4 + lq) ^ sA;
      bf16x8 af[4], bfr[4];
#pragma unroll
      for (int i = 0; i < 4; i++)
        af[i] = *(const bf16x8*)&As[(wm + i * 16 + lm) * BK2 + ph * 8];
#pragma unroll
      for (int j = 0; j < 4; j++)
        bfr[j] = *(const bf16x8*)&Bs[(wn + j * 16 + lm) * BK2 + ph * 8];
#pragma unroll
      for (int i = 0; i < 4; i++)
#pragma unroll
        for (int j = 0; j < 4; j++)
          acc[i][j] = MFMA16(af[i], bfr[j], acc[i][j]);
    }
    __syncthreads();
  }

  // ---- epilogue ----
  constexpr int N = NCT * BN2;
  const float* __restrict__ bv = bias + (size_t)e * N;
  if constexpr (!SCATTER) {
    __bf16* __restrict__ Hq = (__bf16*)outp;
#pragma unroll
    for (int j = 0; j < 4; j++) {
      const int col = nb0 + wn + j * 16 + lm;
      const float bb = bv[col];
#pragma unroll
      for (int i = 0; i < 4; i++) {
#pragma unroll
        for (int r = 0; r < 4; r++) {
          int row = row0 + wm + i * 16 + lq * 4 + r;
          Hq[(size_t)row * N + col] = (__bf16)gelu_f(acc[i][j][r] + bb);
        }
      }
    }
  } else {
    float* __restrict__ O = (float*)outp;
#pragma unroll
    for (int j = 0; j < 4; j++) {
      const int col = nb0 + wn + j * 16 + lm;
      const float bb = bv[col];
#pragma unroll
      for (int i = 0; i < 4; i++) {
#pragma unroll
        for (int r = 0; r < 4; r++) {
          const int t = toks[wm + i * 16 + lq * 4 + r];
          if (t >= 0) O[(size_t)t * DMODEL + col] = acc[i][j][r] + bb;
        }
      }
    }
  }
}

// ================= legacy fast path (kept as ws-budget fallback) =================
__global__ __launch_bounds__(256, 2) void k_gemm1b(
    const __bf16* __restrict__ Ag, const __bf16* __restrict__ Wt,
    const float* __restrict__ b1, const int* __restrict__ po,
    __bf16* __restrict__ H)
{
  __shared__ __align__(16) __bf16 As[BM * BK];
  __shared__ __align__(16) __bf16 Bs[BN * BK];
  const int tid = threadIdx.x;
  const int b = (int)blockIdx.x;
  const int slot = b >> 3;
  const int row_t = (b & 7) + ((slot >> 5) << 3);
  const int col_t = slot & 31;
  const int row0 = row_t * BM;
  if (row0 >= po[NEXP]) return;
  const int nb0 = col_t * BN;

  int e = 0;
#pragma unroll
  for (int k = 1; k < NEXP; k++) e = (row0 >= po[k]) ? k : e;
  const __bf16* __restrict__ B = Wt + (size_t)e * DFF * DMODEL;

  f32x4 acc[4][4];
#pragma unroll
  for (int i = 0; i < 4; i++)
#pragma unroll
    for (int j = 0; j < 4; j++) acc[i][j] = (f32x4)0.0f;

  const int wave = tid >> 6;
  const int lane = tid & 63;
  const int wm = (wave & 1) * 64;
  const int wn = (wave >> 1) * 64;
  const int lm = lane & 15;
  const int lq = lane >> 4;

  const int sr = wave * 32 + (lane >> 2);
  const int g  = (lane & 3) ^ ((lane >> 3) & 3);
  const __bf16* Aptr = Ag + (size_t)(row0 + sr) * DMODEL + g * 8;
  const __bf16* Bptr = B + (size_t)(nb0 + sr) * DMODEL + g * 8;
  __bf16* Al = &As[wave * 1024];
  __bf16* Bl = &Bs[wave * 1024];
  const int sA = (lm >> 1) & 3;

  for (int k0 = 0; k0 < DMODEL; k0 += BK) {
    GLOAD16(Aptr + k0, Al);
    GLOAD16(Aptr + k0 + 16 * DMODEL, Al + 512);
    GLOAD16(Bptr + k0, Bl);
    GLOAD16(Bptr + k0 + 16 * DMODEL, Bl + 512);
    __syncthreads();

    bf16x8 af[4], bfr[4];
#pragma unroll
    for (int i = 0; i < 4; i++)
      af[i] = *(const bf16x8*)&As[(wm + i * 16 + lm) * BK + (lq ^ sA) * 8];
#pragma unroll
    for (int j = 0; j < 4; j++)
      bfr[j] = *(const bf16x8*)&Bs[(wn + j * 16 + lm) * BK + (lq ^ sA) * 8];
#pragma unroll
    for (int i = 0; i < 4; i++)
#pragma unroll
      for (int j = 0; j < 4; j++)
        acc[i][j] = __builtin_amdgcn_mfma_f32_16x16x32_bf16(af[i], bfr[j], acc[i][j], 0, 0, 0);
    __syncthreads();
  }

  const float* __restrict__ b1e = b1 + e * DFF;
#pragma unroll
  for (int j = 0; j < 4; j++) {
    const int col = nb0 + wn + j * 16 + lm;
    const float bias = b1e[col];
#pragma unroll
    for (int i = 0; i < 4; i++) {
#pragma unroll
      for (int r = 0; r < 4; r++) {
        int row = row0 + wm + i * 16 + lq * 4 + r;
        H[(size_t)row * DFF + col] = (__bf16)gelu_f(acc[i][j][r] + bias);
      }
    }
  }
}

__global__ __launch_bounds__(256, 2) void k_gemm2b(
    const __bf16* __restrict__ H, const __bf16* __restrict__ Wt,
    const float* __restrict__ b2, const int* __restrict__ bucket,
    const int* __restrict__ po, float* __restrict__ out)
{
  __shared__ __align__(16) __bf16 As[BM * BK];
  __shared__ __align__(16) __bf16 Bs[BN * BK];
  __shared__ int toks[BM];
  const int tid = threadIdx.x;
  const int b = (int)blockIdx.x;
  const int slot = b >> 3;
  const int row_t = (b & 7) + ((slot >> 3) << 3);
  const int col_t = slot & 7;
  const int row0 = row_t * BM;
  if (row0 >= po[NEXP]) return;
  const int nb0 = col_t * BN;

  int e = 0;
#pragma unroll
  for (int k = 1; k < NEXP; k++) e = (row0 >= po[k]) ? k : e;
  const __bf16* __restrict__ B = Wt + (size_t)e * DMODEL * DFF;

  if (tid < BM) toks[tid] = bucket[row0 + tid];

  f32x4 acc[4][4];
#pragma unroll
  for (int i = 0; i < 4; i++)
#pragma unroll
    for (int j = 0; j < 4; j++) acc[i][j] = (f32x4)0.0f;

  const int wave = tid >> 6;
  const int lane = tid & 63;
  const int wm = (wave & 1) * 64;
  const int wn = (wave >> 1) * 64;
  const int lm = lane & 15;
  const int lq = lane >> 4;

  const int sr = wave * 32 + (lane >> 2);
  const int g  = (lane & 3) ^ ((lane >> 3) & 3);
  const __bf16* Aptr = H + (size_t)(row0 + sr) * DFF + g * 8;
  const __bf16* Bptr = B + (size_t)(nb0 + sr) * DFF + g * 8;
  __bf16* Al = &As[wave * 1024];
  __bf16* Bl = &Bs[wave * 1024];
  const int sA = (lm >> 1) & 3;

  for (int k0 = 0; k0 < DFF; k0 += BK) {
    GLOAD16(Aptr + k0, Al);
    GLOAD16(Aptr + k0 + 16 * DFF, Al + 512);
    GLOAD16(Bptr + k0, Bl);
    GLOAD16(Bptr + k0 + 16 * DFF, Bl + 512);
    __syncthreads();

    bf16x8 af[4], bfr[4];
#pragma unroll
    for (int i = 0; i < 4; i++)
      af[i] = *(const bf16x8*)&As[(wm + i * 16 + lm) * BK + (lq ^ sA) * 8];
#pragma unroll
    for (int j = 0; j < 4; j++)
      bfr[j] = *(const bf16x8*)&Bs[(wn + j * 16 + lm) * BK + (lq ^ sA) * 8];
#pragma unroll
    for (int i = 0; i < 4; i++)
#pragma unroll
      for (int j = 0; j < 4; j++)
        acc[i][j] = __builtin_amdgcn_mfma_f32_16x16x32_bf16(af[i], bfr[j], acc[i][j], 0, 0, 0);
    __syncthreads();
  }

  const float* __restrict__ b2e = b2 + e * DMODEL;
#pragma unroll
  for (int j = 0; j < 4; j++) {
    const int col = nb0 + wn + j * 16 + lm;
    const float bias = b2e[col];
#pragma unroll
    for (int i = 0; i < 4; i++) {
#pragma unroll
      for (int r = 0; r < 4; r++) {
        int t = toks[wm + i * 16 + lq * 4 + r];
        if (t >= 0) out[(size_t)t * DMODEL + col] = acc[i][j][r] + bias;
      }
    }
  }
}

// ================= round-1 fallback path (inline-convert GEMMs) =================
__global__ __launch_bounds__(256, 2) void k_gemm1(
    const float* __restrict__ X, const float* __restrict__ W1,
    const float* __restrict__ b1, const int* __restrict__ bucket,
    const int* __restrict__ po, __bf16* __restrict__ H, int base_row)
{
  __shared__ __bf16 As[BM * LDA];
  __shared__ __bf16 Bs[BN * LDB];
  __shared__ int toks[BM];
  const int tid = threadIdx.x;
  const int total = po[NEXP];
  const int row0 = base_row + (int)blockIdx.x * BM;
  if (row0 >= total) return;
  const int nb0 = (int)blockIdx.y * BN;
  int e = 0;
#pragma unroll
  for (int k = 1; k < NEXP; k++) e = (row0 >= po[k]) ? k : e;
  const float* __restrict__ W = W1 + (size_t)e * DMODEL * DFF;
  if (tid < BM) toks[tid] = bucket[row0 + tid];
  __syncthreads();
  f32x4 acc[4][4];
#pragma unroll
  for (int i = 0; i < 4; i++)
#pragma unroll
    for (int j = 0; j < 4; j++) acc[i][j] = (f32x4)0.0f;
  const int wave = tid >> 6, lane = tid & 63;
  const int wm = (wave & 1) * 64, wn = (wave >> 1) * 64;
  const int lm = lane & 15, lq = lane >> 4;
  const int bn = tid & 127, bkh = (tid >> 7) * 16;
  for (int k0 = 0; k0 < DMODEL; k0 += BK) {
#pragma unroll
    for (int i = 0; i < 4; i++) {
      int idx = tid + i * 256;
      int row = idx >> 3, kq = idx & 7;
      int t = toks[row];
      float4 v = {0.f, 0.f, 0.f, 0.f};
      if (t >= 0) v = *(const float4*)(X + (size_t)t * DMODEL + k0 + kq * 4);
      union { __bf16 h[4]; uint2 u; } cv;
      cv.h[0] = (__bf16)v.x; cv.h[1] = (__bf16)v.y;
      cv.h[2] = (__bf16)v.z; cv.h[3] = (__bf16)v.w;
      *(uint2*)&As[row * LDA + kq * 4] = cv.u;
    }
    {
      const float* src = W + (size_t)(k0 + bkh) * DFF + nb0 + bn;
      bf16x8 b0, b1v;
#pragma unroll
      for (int kk = 0; kk < 8; kk++) b0[kk] = (__bf16)src[(size_t)kk * DFF];
#pragma unroll
      for (int kk = 0; kk < 8; kk++) b1v[kk] = (__bf16)src[(size_t)(kk + 8) * DFF];
      *(bf16x8*)&Bs[bn * LDB + bkh] = b0;
      *(bf16x8*)&Bs[bn * LDB + bkh + 8] = b1v;
    }
    __syncthreads();
    bf16x8 af[4], bfr[4];
#pragma unroll
    for (int i = 0; i < 4; i++)
      af[i] = *(const bf16x8*)&As[(wm + i * 16 + lm) * LDA + lq * 8];
#pragma unroll
    for (int j = 0; j < 4; j++)
      bfr[j] = *(const bf16x8*)&Bs[(wn + j * 16 + lm) * LDB + lq * 8];
#pragma unroll
    for (int i = 0; i < 4; i++)
#pragma unroll
      for (int j = 0; j < 4; j++)
        acc[i][j] = __builtin_amdgcn_mfma_f32_16x16x32_bf16(af[i], bfr[j], acc[i][j], 0, 0, 0);
    __syncthreads();
  }
  const float* __restrict__ b1e = b1 + e * DFF;
  const int hbase = (int)blockIdx.x * BM;
#pragma unroll
  for (int j = 0; j < 4; j++) {
    const int col = nb0 + wn + j * 16 + lm;
    const float bias = b1e[col];
#pragma unroll
    for (int i = 0; i < 4; i++)
#pragma unroll
      for (int r = 0; r < 4; r++) {
        int row = hbase + wm + i * 16 + lq * 4 + r;
        H[(size_t)row * DFF + col] = (__bf16)gelu_f(acc[i][j][r] + bias);
      }
  }
}

__global__ __launch_bounds__(256, 2) void k_gemm2(
    const __bf16* __restrict__ H, const float* __restrict__ W2,
    const float* __restrict__ b2, const int* __restrict__ bucket,
    const int* __restrict__ po, float* __restrict__ out, int base_row)
{
  __shared__ __bf16 As[BM * LDA];
  __shared__ __bf16 Bs[BN * LDB];
  __shared__ int toks[BM];
  const int tid = threadIdx.x;
  const int total = po[NEXP];
  const int row0 = base_row + (int)blockIdx.x * BM;
  if (row0 >= total) return;
  const int nb0 = (int)blockIdx.y * BN;
  int e = 0;
#pragma unroll
  for (int k = 1; k < NEXP; k++) e = (row0 >= po[k]) ? k : e;
  const float* __restrict__ W = W2 + (size_t)e * DFF * DMODEL;
  if (tid < BM) toks[tid] = bucket[row0 + tid];
  __syncthreads();
  f32x4 acc[4][4];
#pragma unroll
  for (int i = 0; i < 4; i++)
#pragma unroll
    for (int j = 0; j < 4; j++) acc[i][j] = (f32x4)0.0f;
  const int wave = tid >> 6, lane = tid & 63;
  const int wm = (wave & 1) * 64, wn = (wave >> 1) * 64;
  const int lm = lane & 15, lq = lane >> 4;
  const int bn = tid & 127, bkh = (tid >> 7) * 16;
  const int hbase = (int)blockIdx.x * BM;
  for (int k0 = 0; k0 < DFF; k0 += BK) {
#pragma unroll
    for (int i = 0; i < 2; i++) {
      int idx = tid + i * 256;
      int row = idx >> 2, kq = idx & 3;
      bf16x8 v = *(const bf16x8*)(H + (size_t)(hbase + row) * DFF + k0 + kq * 8);
      *(bf16x8*)&As[row * LDA + kq * 8] = v;
    }
    {
      const float* src = W + (size_t)(k0 + bkh) * DMODEL + nb0 + bn;
      bf16x8 b0, b1v;
#pragma unroll
      for (int kk = 0; kk < 8; kk++) b0[kk] = (__bf16)src[(size_t)kk * DMODEL];
#pragma unroll
      for (int kk = 0; kk < 8; kk++) b1v[kk] = (__bf16)src[(size_t)(kk + 8) * DMODEL];
      *(bf16x8*)&Bs[bn * LDB + bkh] = b0;
      *(bf16x8*)&Bs[bn * LDB + bkh + 8] = b1v;
    }
    __syncthreads();
    bf16x8 af[4], bfr[4];
#pragma unroll
    for (int i = 0; i < 4; i++)
      af[i] = *(const bf16x8*)&As[(wm + i * 16 + lm) * LDA + lq * 8];
#pragma unroll
    for (int j = 0; j < 4; j++)
      bfr[j] = *(const bf16x8*)&Bs[(wn + j * 16 + lm) * LDB + lq * 8];
#pragma unroll
    for (int i = 0; i < 4; i++)
#pragma unroll
      for (int j = 0; j < 4; j++)
        acc[i][j] = __builtin_amdgcn_mfma_f32_16x16x32_bf16(af[i], bfr[j], acc[i][j], 0, 0, 0);
    __syncthreads();
  }
  const float* __restrict__ b2e = b2 + e * DMODEL;
#pragma unroll
  for (int j = 0; j < 4; j++) {
    const int col = nb0 + wn + j * 16 + lm;
    const float bias = b2e[col];
#pragma unroll
    for (int i = 0; i < 4; i++)
#pragma unroll
      for (int r = 0; r < 4; r++) {
        int t = toks[wm + i * 16 + lq * 4 + r];
        if (t >= 0) out[(size_t)t * DMODEL + col] = acc[i][j][r] + bias;
      }
  }
}

__global__ __launch_bounds__(256) void k_fallback(
    const float* __restrict__ X, const int* __restrict__ idx,
    const float* __restrict__ W1, const float* __restrict__ b1,
    const float* __restrict__ W2, const float* __restrict__ b2,
    float* __restrict__ out)
{
  __shared__ float xs[DMODEL];
  __shared__ float hs[DFF];
  const int t = blockIdx.x;
  const int e = idx[t];
  const int tid = threadIdx.x;
  const float* w1 = W1 + (size_t)e * DMODEL * DFF;
  const float* w2 = W2 + (size_t)e * DFF * DMODEL;
  for (int i = tid; i < DMODEL; i += 256) xs[i] = X[(size_t)t * DMODEL + i];
  __syncthreads();
  for (int f = tid; f < DFF; f += 256) {
    float a = 0.f;
    for (int d = 0; d < DMODEL; d++) a += xs[d] * w1[(size_t)d * DFF + f];
    hs[f] = gelu_f(a + b1[e * DFF + f]);
  }
  __syncthreads();
  for (int d = tid; d < DMODEL; d += 256) {
    float a = 0.f;
    for (int f = 0; f < DFF; f++) a += hs[f] * w2[(size_t)f * DMODEL + d];
    out[(size_t)t * DMODEL + d] = a + b2[e * DMODEL + d];
  }
}

extern "C" void kernel_launch(void* const* d_in, const int* in_sizes, int n_in,
                              void* d_out, int out_size, void* d_ws, size_t ws_size,
                              hipStream_t stream) {
  const float* X  = (const float*)d_in[0];
  const int*   EI = (const int*)d_in[1];
  const float* W1 = (const float*)d_in[2];
  const float* b1 = (const float*)d_in[3];
  const float* W2 = (const float*)d_in[4];
  const float* b2 = (const float*)d_in[5];
  float* out = (float*)d_out;

  char* ws = (char*)d_ws;
  int* counts  = (int*)(ws + 0);
  int* cursors = (int*)(ws + 32);
  int* po      = (int*)(ws + 64);
  int* bucket  = (int*)(ws + 512);

  // ---- 256-row-tile path (expert segments padded to 256) ----
  {
    const size_t XG_OFF2 = 512 + (size_t)TP256 * 4;                    // 74240
    const size_t WT_OFF2 = XG_OFF2 + (size_t)TP256 * DMODEL * 2;
    const size_t HF_OFF2 = WT_OFF2 + (size_t)NEXP * DMODEL * DFF * 2;
    const size_t NEED2   = HF_OFF2 + (size_t)TP256 * DFF * 2;          // ~255.9 MB
    if (ws_size >= NEED2) {
      __bf16* Xg = (__bf16*)(ws + XG_OFF2);
      __bf16* Wt = (__bf16*)(ws + WT_OFF2);
      __bf16* H  = (__bf16*)(ws + HF_OFF2);

      k_init<<<(TP256 + 255) / 256, 256, 0, stream>>>(counts, cursors, bucket, TP256);
      k_hist<<<(T_TOK + 255) / 256, 256, 0, stream>>>(EI, counts);
      k_scan<<<1, 64, 0, stream>>>(counts, po, SEG8);
      k_scatter<<<(T_TOK + 255) / 256, 256, 0, stream>>>(EI, po, cursors, bucket);
      k_gather<<<TP256, 256, 0, stream>>>(X, bucket, Xg);
      k_transpose<<<dim3(DFF / 64, DMODEL / 64, NEXP), 256, 0, stream>>>(W1, Wt, DMODEL, DFF);
      k_gemm2p<DMODEL, DFF / BN2, false>
          <<<(TP256 / BM2) * (DFF / BN2), 512, 0, stream>>>(Xg, Wt, b1, bucket, po, (void*)H);
      k_transpose<<<dim3(DMODEL / 64, DFF / 64, NEXP), 256, 0, stream>>>(W2, Wt, DFF, DMODEL);
      k_gemm2p<DFF, DMODEL / BN2, true>
          <<<(TP256 / BM2) * (DMODEL / BN2), 512, 0, stream>>>(H, Wt, b2, bucket, po, (void*)out);
      return;
    }
  }

  const int Tpad = TPAD;  // 17408

  const size_t XG_OFF = 70144;
  const size_t XG_SZ  = (size_t)Tpad * DMODEL * 2;
  const size_t WT_OFF = XG_OFF + XG_SZ;
  const size_t WT_SZ  = (size_t)NEXP * DMODEL * DFF * 2;
  const size_t HF_OFF = WT_OFF + WT_SZ;
  const size_t H_SZ   = (size_t)Tpad * DFF * 2;
  const size_t NEED   = HF_OFF + H_SZ;   // ~245.4 MB

  if (ws_size >= NEED) {
    __bf16* Xg = (__bf16*)(ws + XG_OFF);
    __bf16* Wt = (__bf16*)(ws + WT_OFF);
    __bf16* H  = (__bf16*)(ws + HF_OFF);

    k_init<<<(Tpad + 255) / 256, 256, 0, stream>>>(counts, cursors, bucket, Tpad);
    k_hist<<<(T_TOK + 255) / 256, 256, 0, stream>>>(EI, counts);
    k_scan<<<1, 64, 0, stream>>>(counts, po, BM);
    k_scatter<<<(T_TOK + 255) / 256, 256, 0, stream>>>(EI, po, cursors, bucket);
    k_gather<<<Tpad, 256, 0, stream>>>(X, bucket, Xg);
    k_transpose<<<dim3(DFF / 64, DMODEL / 64, NEXP), 256, 0, stream>>>(W1, Wt, DMODEL, DFF);
    k_gemm1b<<<(Tpad / BM) * (DFF / BN), 256, 0, stream>>>(Xg, Wt, b1, po, H);
    k_transpose<<<dim3(DMODEL / 64, DFF / 64, NEXP), 256, 0, stream>>>(W2, Wt, DFF, DMODEL);
    k_gemm2b<<<(Tpad / BM) * (DMODEL / BN), 256, 0, stream>>>(H, Wt, b2, bucket, po, out);
    return;
  }

  // ---- round-1 fallback path ----
  const size_t H_OFF = 512 + (size_t)Tpad * 4;
  __bf16* H = (__bf16*)(ws + H_OFF);
  size_t avail = (ws_size > H_OFF) ? ws_size - H_OFF : 0;
  long long crll = (long long)(avail / ((size_t)DFF * 2));
  int CR = (crll > Tpad) ? Tpad : (int)crll;
  CR -= CR % BM;
  if (CR < BM) {
    k_fallback<<<T_TOK, 256, 0, stream>>>(X, EI, W1, b1, W2, b2, out);
    return;
  }
  k_init<<<(Tpad + 255) / 256, 256, 0, stream>>>(counts, cursors, bucket, Tpad);
  k_hist<<<(T_TOK + 255) / 256, 256, 0, stream>>>(EI, counts);
  k_scan<<<1, 64, 0, stream>>>(counts, po, BM);
  k_scatter<<<(T_TOK + 255) / 256, 256, 0, stream>>>(EI, po, cursors, bucket);
  int nchunks = (Tpad + CR - 1) / CR;
  for (int c = 0; c < nchunks; c++) {
    int base = c * CR;
    int rows = Tpad - base; if (rows > CR) rows = CR;
    int mt = rows / BM;
    k_gemm1<<<dim3(mt, DFF / BN), 256, 0, stream>>>(X, W1, b1, bucket, po, H, base);
    k_gemm2<<<dim3(mt, DMODEL / BN), 256, 0, stream>>>(H, W2, b2, bucket, po, out, base);
  }
}